// Round 12
// baseline (126.704 us; speedup 1.0000x reference)
//
#include <hip/hip_runtime.h>
#include <hip/hip_bf16.h>
#include <cstddef>

#define SEQ 2048
#define DM  512
#define NH  8
#define DKH 64
#define DFF 2048
#define NB  2
#define MR  (NB*SEQ)   // 4096 rows

typedef __attribute__((ext_vector_type(8)))  short short8;
typedef __attribute__((ext_vector_type(4)))  float f32x4;
typedef __attribute__((ext_vector_type(16))) float f32x16;

#define AS1(p) ((const __attribute__((address_space(1))) void*)(p))
#define AS3(p) ((__attribute__((address_space(3))) void*)(p))

// Q pre-scale: 1/sqrt(64) * log2(e)
#define QSCALE 0.180336880f
// Fixed softmax max (exp2 domain); uniform 2^-SMAX cancels in o/l.
#define SMAX 16.0f

__device__ inline unsigned cvtpk(float lo, float hi) {
  unsigned r;
  asm("v_cvt_pk_bf16_f32 %0, %1, %2" : "=v"(r) : "v"(lo), "v"(hi));
  return r;
}

// ---------------------------------------------------------------------------
// f32 -> bf16 conversion + weight packing
// ---------------------------------------------------------------------------
__device__ inline void cvt8(const float* __restrict__ s, __hip_bfloat16* __restrict__ d) {
  float4 a = *reinterpret_cast<const float4*>(s);
  float4 b = *reinterpret_cast<const float4*>(s + 4);
  union { __hip_bfloat16 h[8]; short8 v; } u;
  u.h[0] = __float2bfloat16(a.x); u.h[1] = __float2bfloat16(a.y);
  u.h[2] = __float2bfloat16(a.z); u.h[3] = __float2bfloat16(a.w);
  u.h[4] = __float2bfloat16(b.x); u.h[5] = __float2bfloat16(b.y);
  u.h[6] = __float2bfloat16(b.z); u.h[7] = __float2bfloat16(b.w);
  *reinterpret_cast<short8*>(d) = u.v;
}

__global__ __launch_bounds__(256) void cvt_all(
    const float* __restrict__ x,
    const float* __restrict__ Wq, const float* __restrict__ Wk,
    const float* __restrict__ Wv, const float* __restrict__ Wo,
    const float* __restrict__ W1, const float* __restrict__ W2,
    const float* __restrict__ bq, const float* __restrict__ bk,
    const float* __restrict__ bv,
    __hip_bfloat16* __restrict__ xb,  __hip_bfloat16* __restrict__ wqkv,
    __hip_bfloat16* __restrict__ wob, __hip_bfloat16* __restrict__ w1b,
    __hip_bfloat16* __restrict__ w2b, float* __restrict__ bqkv)
{
  const int u = blockIdx.x * 256 + threadIdx.x;   // unit of 8 elems
  if (u < 262144) {
    cvt8(x + (size_t)u * 8, xb + (size_t)u * 8);
  } else if (u < 360448) {                         // wqkv: 1536*512 packed
    const int d = (u - 262144) * 8;
    const int n = d >> 9, k = d & 511;
    const float* src = (n < 512) ? (Wq + (size_t)n * 512 + k)
                     : (n < 1024) ? (Wk + (size_t)(n - 512) * 512 + k)
                                  : (Wv + (size_t)(n - 1024) * 512 + k);
    cvt8(src, wqkv + d);
  } else if (u < 393216) {
    const int d = (u - 360448) * 8; cvt8(Wo + d, wob + d);
  } else if (u < 524288) {
    const int d = (u - 393216) * 8; cvt8(W1 + d, w1b + d);
  } else if (u < 655360) {
    const int d = (u - 524288) * 8; cvt8(W2 + d, w2b + d);
  } else if (u < 655552) {
    const int d = (u - 655360) * 8;
    const float* src = (d < 512) ? (bq + d) : (d < 1024) ? (bk + d - 512) : (bv + d - 1024);
    *reinterpret_cast<float4*>(bqkv + d)     = *reinterpret_cast<const float4*>(src);
    *reinterpret_cast<float4*>(bqkv + d + 4) = *reinterpret_cast<const float4*>(src + 4);
  }
}

// ---------------------------------------------------------------------------
// bf16 MFMA GEMM (NT), 128xBN tile (BN in {128,64}), BK=64 double-buffered,
// 16x16x32 MFMA (R10-proven). BN=64 halves the tile to double block count
// for the skinny N=512 GEMMs (O-proj, FFN2): 1 -> 2 blocks/CU.
// WVT=1 (QKV, BN=128 only): Q*QSCALE,K -> qkbO[4096][1024]; V -> vtO transposed.
// SPLITK=2: blockIdx.z K-half -> f32 partials Cout/Cout1, bias in z=0 only.
// ---------------------------------------------------------------------------
template<int BN, int OUT_BF16, int RELU, int WVT, int SPLITK>
__global__ __launch_bounds__(256) void gemm_bt(
    const __hip_bfloat16* __restrict__ A, const __hip_bfloat16* __restrict__ Bt,
    const float* __restrict__ bias, void* __restrict__ Cout, void* __restrict__ Cout1,
    __hip_bfloat16* __restrict__ qkbO, __hip_bfloat16* __restrict__ vtO,
    int M, int N, int K)
{
  constexpr int NJ    = BN / 32;             // B fragments per wave (4 or 2)
  constexpr int BUFSZ = 16384 + BN * 128;    // A 16KB + B BN*128
  __shared__ __align__(16) char lds[2 * BUFSZ];
  const int t = threadIdx.x, lane = t & 63, w = t >> 6;
  const int m0 = blockIdx.y * 128, n0 = blockIdx.x * BN;
  const int wm = w >> 1, wn = w & 1;
  const int z = (SPLITK == 2) ? blockIdx.z : 0;
  const int Keff = (SPLITK == 2) ? (K >> 1) : K;
  const int koff = z * Keff;
  const int g = lane >> 4;

  // staging: 32 rows/issue, 8 chunks of 16B per row, source pre-swizzled
  const int r0   = t >> 3;                         // 0..31
  const int kofs = ((lane & 7) ^ (r0 & 7)) * 8;    // elem offset (swizzled)
  const __hip_bfloat16* ap = A  + (size_t)(m0 + r0) * K + koff + kofs;
  const __hip_bfloat16* bp = Bt + (size_t)(n0 + r0) * K + koff + kofs;
  const int ldsoff = t * 16;

  // fragment reads: row*128B + (chunk ^ (row&7))*16
  const int fA = (wm * 64 + (lane & 15)) * 128;
  const int fB = (wn * (BN / 2) + (lane & 15)) * 128;
  const int sw = lane & 7;

  f32x4 acc[4][NJ] = {};
  const int nkt = Keff >> 6;   // K-steps of 64; even for all our shapes

  auto STAGE = [&](int buf, int kt) {
    const size_t ko = (size_t)kt * 64;
    char* bb = lds + buf * BUFSZ;
#pragma unroll
    for (int ii = 0; ii < 4; ++ii)
      __builtin_amdgcn_global_load_lds(AS1(ap + (size_t)ii * 32 * K + ko), AS3(bb + ii * 4096 + ldsoff), 16, 0, 0);
#pragma unroll
    for (int ii = 0; ii < NJ; ++ii)
      __builtin_amdgcn_global_load_lds(AS1(bp + (size_t)ii * 32 * K + ko), AS3(bb + 16384 + ii * 4096 + ldsoff), 16, 0, 0);
  };
  auto COMPUTE = [&](const char* bb) {
    const char* Ab = bb;
    const char* Bb = bb + 16384;
#pragma unroll
    for (int kk = 0; kk < 2; ++kk) {
      const int cx = ((kk * 4 + g) ^ sw) * 16;
      short8 af[4], bf[NJ];
#pragma unroll
      for (int i = 0; i < 4; ++i)  af[i] = *reinterpret_cast<const short8*>(Ab + fA + i * 2048 + cx);
#pragma unroll
      for (int j = 0; j < NJ; ++j) bf[j] = *reinterpret_cast<const short8*>(Bb + fB + j * 2048 + cx);
      __builtin_amdgcn_s_setprio(1);
#pragma unroll
      for (int i = 0; i < 4; ++i)
#pragma unroll
        for (int j = 0; j < NJ; ++j)
          acc[i][j] = __builtin_amdgcn_mfma_f32_16x16x32_bf16(af[i], bf[j], acc[i][j], 0, 0, 0);
      __builtin_amdgcn_s_setprio(0);
    }
  };

  STAGE(0, 0);
  __syncthreads();
  for (int kt = 0; kt < nkt; kt += 2) {
    STAGE(1, kt + 1 < nkt ? kt + 1 : kt);
    COMPUTE(lds);
    __syncthreads();
    STAGE(0, kt + 2 < nkt ? kt + 2 : kt);   // clamp: dummy in-bounds restage
    COMPUTE(lds + BUFSZ);
    __syncthreads();
  }

  float bcol[NJ];
#pragma unroll
  for (int j = 0; j < NJ; ++j)
    bcol[j] = (SPLITK == 2 && z) ? 0.f : bias[n0 + wn * (BN / 2) + j * 16 + (lane & 15)];

  if (WVT && n0 >= 1024) {
#pragma unroll
    for (int i = 0; i < 4; ++i) {
      const int r = m0 + wm * 64 + i * 16 + (g << 2);
      const int bb = r >> 11, s = r & 2047;
#pragma unroll
      for (int j = 0; j < NJ; ++j) {
        const int hd = n0 + wn * (BN / 2) + j * 16 + (lane & 15) - 1024;
        union { __hip_bfloat16 h[4]; uint2 uu; } pk;
#pragma unroll
        for (int jj = 0; jj < 4; ++jj) pk.h[jj] = __float2bfloat16(acc[i][j][jj] + bcol[j]);
        *reinterpret_cast<uint2*>(vtO + ((size_t)(bb * 8 + (hd >> 6)) * 64 + (hd & 63)) * SEQ + s) = pk.uu;
      }
    }
    return;
  }

  const float qsc = (WVT && n0 < 512) ? QSCALE : 1.0f;
#pragma unroll
  for (int i = 0; i < 4; ++i) {
    const int row = m0 + wm * 64 + i * 16 + (g << 2);
#pragma unroll
    for (int j = 0; j < NJ; ++j) {
      const int col = n0 + wn * (BN / 2) + j * 16 + (lane & 15);
#pragma unroll
      for (int jj = 0; jj < 4; ++jj) {
        float v = acc[i][j][jj] + bcol[j];
        if (RELU) v = fmaxf(v, 0.f);
        if (WVT)
          qkbO[(size_t)(row + jj) * 1024 + col] = __float2bfloat16(v * qsc);
        else if (OUT_BF16)
          ((__hip_bfloat16*)Cout)[(size_t)(row + jj) * N + col] = __float2bfloat16(v);
        else {
          float* dst = (float*)((SPLITK == 2 && z) ? Cout1 : Cout);
          dst[(size_t)(row + jj) * N + col] = v;
        }
      }
    }
  }
}

// ---------------------------------------------------------------------------
// MFMA flash attention, 32x32 swapped operands, P in registers, FIXED-MAX
// softmax. grid=(16 q-tiles of 128, 16 bh, 4 s-quarters). (unchanged, R10)
// ---------------------------------------------------------------------------
__global__ __launch_bounds__(256) void attn_mfma(
    const __hip_bfloat16* __restrict__ qkb, const __hip_bfloat16* __restrict__ vtb,
    __hip_bfloat16* __restrict__ po, float* __restrict__ pl)
{
  __shared__ __align__(16) char lds[32768];
  char* ks = lds;            // 2 x 8KB K  [64 s][128B d], byte^=(s&7)<<4
  char* vT = lds + 16384;    // 2 x 8KB V^T[64 d][128B s], byte^=(d&7)<<4

  const int t = threadIdx.x, lane = t & 63, w = t >> 6;
  const int qt = blockIdx.x, bh = blockIdx.y, z = blockIdx.z;
  const int b = bh >> 3, h = bh & 7;
  const int ST0 = z * (SEQ / 4);
  const int NT = SEQ / 4 / 64;   // 8 (even)
  const int l31 = lane & 31, hi = lane >> 5;
  const int swz = (lane & 7) << 4;
  const int hi16 = hi * 16;

  const __hip_bfloat16* Qg = qkb + (size_t)b * SEQ * 1024 + h * DKH;
  const int qrow = qt * 128 + w * 32 + l31;
  short8 qf[4];
#pragma unroll
  for (int kc = 0; kc < 4; ++kc)
    qf[kc] = *reinterpret_cast<const short8*>(Qg + (size_t)qrow * 1024 + kc * 16 + hi * 8);

  const int srow = t >> 3;
  const int sofs = ((lane & 7) ^ (srow & 7)) * 8;
  const __hip_bfloat16* kbase = qkb + (size_t)(b * SEQ + ST0 + srow) * 1024 + 512 + h * DKH + sofs;
  const __hip_bfloat16* vbase = vtb + ((size_t)bh * 64 + srow) * SEQ + ST0 + sofs;
  const int ldso = t * 16;

  f32x16 o0 = {}, o1 = {};
  float l_ = 0.f;

  auto STAGE_K = [&](int buf, int st) {
    const size_t ko = (size_t)st * 64 * 1024;
    char* kd = ks + buf * 8192 + ldso;
    __builtin_amdgcn_global_load_lds(AS1(kbase + ko),                     AS3(kd),        16, 0, 0);
    __builtin_amdgcn_global_load_lds(AS1(kbase + ko + (size_t)32 * 1024), AS3(kd + 4096), 16, 0, 0);
  };
  auto STAGE_V = [&](int buf, int st) {
    const size_t vo = (size_t)st * 64;
    char* vd = vT + buf * 8192 + ldso;
    __builtin_amdgcn_global_load_lds(AS1(vbase + vo),                    AS3(vd),        16, 0, 0);
    __builtin_amdgcn_global_load_lds(AS1(vbase + vo + (size_t)32 * SEQ), AS3(vd + 4096), 16, 0, 0);
  };

  auto TILE = [&](const char* kb_, const char* vb_) {
#pragma unroll
    for (int half = 0; half < 2; ++half) {
      const int rbase = (half * 32 + l31) * 128;

      f32x16 acc = {};
      __builtin_amdgcn_s_setprio(1);
#pragma unroll
      for (int kc = 0; kc < 4; ++kc) {
        const int kbyte = (kc * 32 + hi16) ^ swz;
        const short8 ka = *reinterpret_cast<const short8*>(kb_ + rbase + kbyte);
        acc = __builtin_amdgcn_mfma_f32_32x32x16_bf16(ka, qf[kc], acc, 0, 0, 0);
      }
      __builtin_amdgcn_s_setprio(0);

      short8 pf[2];
      float ps = 0.f;
#pragma unroll
      for (int sc = 0; sc < 2; ++sc) {
        const int rb = sc * 8;
        float e0 = exp2f(acc[rb+0] - SMAX), e1 = exp2f(acc[rb+1] - SMAX);
        float e2 = exp2f(acc[rb+2] - SMAX), e3 = exp2f(acc[rb+3] - SMAX);
        float e4 = exp2f(acc[rb+4] - SMAX), e5 = exp2f(acc[rb+5] - SMAX);
        float e6 = exp2f(acc[rb+6] - SMAX), e7 = exp2f(acc[rb+7] - SMAX);
        ps += ((e0 + e1) + (e2 + e3)) + ((e4 + e5) + (e6 + e7));
        unsigned w0 = cvtpk(e0, e1), w1 = cvtpk(e2, e3);
        unsigned w2 = cvtpk(e4, e5), w3 = cvtpk(e6, e7);
        asm("v_permlane32_swap_b32 %0, %1" : "+v"(w0), "+v"(w2));
        asm("v_permlane32_swap_b32 %0, %1" : "+v"(w1), "+v"(w3));
        union { unsigned u[4]; short8 s8; } pu;
        pu.u[0] = w0; pu.u[1] = w1; pu.u[2] = w2; pu.u[3] = w3;
        pf[sc] = pu.s8;
      }
      ps += __shfl_xor(ps, 32);
      l_ += ps;

      __builtin_amdgcn_s_setprio(1);
#pragma unroll
      for (int kc = 0; kc < 2; ++kc) {
        const int sbyte = (half * 64 + kc * 32 + hi16) ^ swz;
        const short8 va0 = *reinterpret_cast<const short8*>(vb_ + l31 * 128 + sbyte);
        const short8 va1 = *reinterpret_cast<const short8*>(vb_ + (32 + l31) * 128 + sbyte);
        o0 = __builtin_amdgcn_mfma_f32_32x32x16_bf16(va0, pf[kc], o0, 0, 0, 0);
        o1 = __builtin_amdgcn_mfma_f32_32x32x16_bf16(va1, pf[kc], o1, 0, 0, 0);
      }
      __builtin_amdgcn_s_setprio(0);
    }
  };

  STAGE_K(0, 0);
  STAGE_V(0, 0);
  __syncthreads();

  for (int st = 0; st < NT; st += 2) {
    STAGE_V(1, st + 1);
    STAGE_K(1, st + 1);
    TILE(ks, vT);
    __syncthreads();
    const int nx = st + 2 < NT ? st + 2 : st + 1;
    STAGE_V(0, nx);
    STAGE_K(0, nx);
    TILE(ks + 8192, vT + 8192);
    __syncthreads();
  }

  {
    __hip_bfloat16* pz = po + (size_t)z * MR * DM;
    const size_t orow = (size_t)b * SEQ + qt * 128 + w * 32 + l31;
    __hip_bfloat16* dst = pz + orow * DM + h * DKH;
#pragma unroll
    for (int r = 0; r < 4; ++r) {
      uint2 u0, u1;
      u0.x = cvtpk(o0[4*r+0], o0[4*r+1]); u0.y = cvtpk(o0[4*r+2], o0[4*r+3]);
      u1.x = cvtpk(o1[4*r+0], o1[4*r+1]); u1.y = cvtpk(o1[4*r+2], o1[4*r+3]);
      *reinterpret_cast<uint2*>(dst + r * 8 + hi * 4)      = u0;
      *reinterpret_cast<uint2*>(dst + 32 + r * 8 + hi * 4) = u1;
    }
  }
  if (lane < 32) {
    const size_t idx = ((size_t)z * 16 + bh) * SEQ + qt * 128 + w * 32 + lane;
    pl[idx] = l_;
  }
}

// ---------------------------------------------------------------------------
// combine four s-quarters (bf16 partials, common fixed-max scale) ->
// attnb bf16 [4096][512]: straight sums, no m-merge.
// ---------------------------------------------------------------------------
__global__ __launch_bounds__(256) void attn_combine(
    const __hip_bfloat16* __restrict__ po, const float* __restrict__ pl,
    __hip_bfloat16* __restrict__ attnb)
{
  const int row  = blockIdx.x * 4 + (threadIdx.x >> 6);
  const int lane = threadIdx.x & 63;
  const int d0 = lane * 8, h = lane >> 3;
  const int b = row >> 11, qq = row & 2047;
  const size_t idx = ((size_t)b * 8 + h) * SEQ + qq;
  const size_t zs = (size_t)16 * SEQ;
  const float inv = 1.0f / (pl[idx] + pl[idx + zs] + pl[idx + 2*zs] + pl[idx + 3*zs]);
  float acc[8] = {};
  const size_t ro = (size_t)row * DM + d0;
#pragma unroll
  for (int zz = 0; zz < 4; ++zz) {
    short8 v = *reinterpret_cast<const short8*>(po + (size_t)zz * MR * DM + ro);
#pragma unroll
    for (int j = 0; j < 8; ++j) {
      const unsigned uu = ((unsigned)(unsigned short)v[j]) << 16;
      acc[j] += __builtin_bit_cast(float, uu);
    }
  }
  union { __hip_bfloat16 hh[8]; short8 s8; } u;
#pragma unroll
  for (int j = 0; j < 8; ++j) u.hh[j] = __float2bfloat16(acc[j] * inv);
  *reinterpret_cast<short8*>(attnb + ro) = u.s8;
}

// ---------------------------------------------------------------------------
// out = LayerNorm(X + Y0 + Y1) * g + be ; optional bf16 copy. One wave/row.
// ---------------------------------------------------------------------------
template<int WB>
__global__ __launch_bounds__(256) void ln_res(
    const float* __restrict__ X, const float* __restrict__ Y0,
    const float* __restrict__ Y1,
    const float* __restrict__ g, const float* __restrict__ be,
    float* __restrict__ out, __hip_bfloat16* __restrict__ outb)
{
  const int row  = blockIdx.x * 4 + (threadIdx.x >> 6);
  const int lane = threadIdx.x & 63;
  const int c0   = lane * 8;
  const float* xr = X  + (size_t)row * DM;
  const float* y0 = Y0 + (size_t)row * DM;
  const float* y1 = Y1 + (size_t)row * DM;

  float v[8];
  float4 a0 = *reinterpret_cast<const float4*>(xr + c0);
  float4 a1 = *reinterpret_cast<const float4*>(xr + c0 + 4);
  float4 b0 = *reinterpret_cast<const float4*>(y0 + c0);
  float4 b1 = *reinterpret_cast<const float4*>(y0 + c0 + 4);
  float4 c0v= *reinterpret_cast<const float4*>(y1 + c0);
  float4 c1v= *reinterpret_cast<const float4*>(y1 + c0 + 4);
  v[0]=a0.x+b0.x+c0v.x; v[1]=a0.y+b0.y+c0v.y; v[2]=a0.z+b0.z+c0v.z; v[3]=a0.w+b0.w+c0v.w;
  v[4]=a1.x+b1.x+c1v.x; v[5]=a1.y+b1.y+c1v.y; v[6]=a1.z+b1.z+c1v.z; v[7]=a1.w+b1.w+c1v.w;

  float s = 0.f;
#pragma unroll
  for (int i = 0; i < 8; ++i) s += v[i];
#pragma unroll
  for (int off = 32; off >= 1; off >>= 1) s += __shfl_xor(s, off);
  const float mu = s * (1.0f/512.0f);

  float ss = 0.f;
#pragma unroll
  for (int i = 0; i < 8; ++i) { const float d = v[i] - mu; ss += d*d; }
#pragma unroll
  for (int off = 32; off >= 1; off >>= 1) ss += __shfl_xor(ss, off);
  const float rs = rsqrtf(ss * (1.0f/512.0f) + 1e-5f);

  float4 g0 = *reinterpret_cast<const float4*>(g  + c0);
  float4 g1 = *reinterpret_cast<const float4*>(g  + c0 + 4);
  float4 e0 = *reinterpret_cast<const float4*>(be + c0);
  float4 e1 = *reinterpret_cast<const float4*>(be + c0 + 4);
  float r[8];
  r[0]=(v[0]-mu)*rs*g0.x+e0.x; r[1]=(v[1]-mu)*rs*g0.y+e0.y;
  r[2]=(v[2]-mu)*rs*g0.z+e0.z; r[3]=(v[3]-mu)*rs*g0.w+e0.w;
  r[4]=(v[4]-mu)*rs*g1.x+e1.x; r[5]=(v[5]-mu)*rs*g1.y+e1.y;
  r[6]=(v[6]-mu)*rs*g1.z+e1.z; r[7]=(v[7]-mu)*rs*g1.w+e1.w;
  float4 o0, o1;
  o0.x=r[0]; o0.y=r[1]; o0.z=r[2]; o0.w=r[3];
  o1.x=r[4]; o1.y=r[5]; o1.z=r[6]; o1.w=r[7];
  *reinterpret_cast<float4*>(out + (size_t)row * DM + c0)     = o0;
  *reinterpret_cast<float4*>(out + (size_t)row * DM + c0 + 4) = o1;
  if (WB) {
    union { __hip_bfloat16 h[8]; short8 vv; } u;
#pragma unroll
    for (int i = 0; i < 8; ++i) u.h[i] = __float2bfloat16(r[i]);
    *reinterpret_cast<short8*>(outb + (size_t)row * DM + c0) = u.vv;
  }
}

// ---------------------------------------------------------------------------
extern "C" void kernel_launch(void* const* d_in, const int* in_sizes, int n_in,
                              void* d_out, int out_size, void* d_ws, size_t ws_size,
                              hipStream_t stream)
{
  const float* x   = (const float*)d_in[0];
  const float* Wq  = (const float*)d_in[1];
  const float* bq  = (const float*)d_in[2];
  const float* Wk  = (const float*)d_in[3];
  const float* bk  = (const float*)d_in[4];
  const float* Wv  = (const float*)d_in[5];
  const float* bv  = (const float*)d_in[6];
  const float* Wo  = (const float*)d_in[7];
  const float* bo  = (const float*)d_in[8];
  const float* W1  = (const float*)d_in[9];
  const float* b1  = (const float*)d_in[10];
  const float* W2  = (const float*)d_in[11];
  const float* b2  = (const float*)d_in[12];
  const float* g1  = (const float*)d_in[13];
  const float* be1 = (const float*)d_in[14];
  const float* g2  = (const float*)d_in[15];
  const float* be2 = (const float*)d_in[16];
  float* out = (float*)d_out;

  // workspace layout (bytes; regions reused across phases)
  char* p = (char*)d_ws;
  __hip_bfloat16* xb    = (__hip_bfloat16*)p;  p += 4194304;   // [4096][512]
  __hip_bfloat16* wqkv  = (__hip_bfloat16*)p;  p += 1572864;   // [1536][512]
  __hip_bfloat16* wob   = (__hip_bfloat16*)p;  p += 524288;    // [512][512]
  __hip_bfloat16* w1b   = (__hip_bfloat16*)p;  p += 2097152;   // [2048][512]
  __hip_bfloat16* w2b   = (__hip_bfloat16*)p;  p += 2097152;   // [512][2048]
  float*          bqkv  = (float*)p;           p += 8192;      // [1536]
  __hip_bfloat16* qkb   = (__hip_bfloat16*)p;  p += 8388608;   // [4096][1024] -> x1 f32
  __hip_bfloat16* vtb   = (__hip_bfloat16*)p;  p += 4194304;   // [16][64][2048] -> attnb
  __hip_bfloat16* pob   = (__hip_bfloat16*)p;  p += 16777216;  // [4][4096][512] bf16 -> opa, f1b
  float*          pl    = (float*)p;           p += 524288;    // [4][16][2048]
  float*          oproj = (float*)p;           p += 8388608;   // oproj z1 / ffn2 z1 partial
  __hip_bfloat16* x1b   = (__hip_bfloat16*)p;  p += 4194304;   // [4096][512]

  float*          x1    = (float*)qkb;            // reuse: qkb dead after attention
  __hip_bfloat16* attnb = (__hip_bfloat16*)vtb;   // reuse: vtb dead after attention
  float*          opa   = (float*)pob;            // pob attn partials dead after combine
  __hip_bfloat16* f1b   = pob;                    // opa dead after ln1
  float*          y2a   = (float*)d_ws;           // [0, 8388608) ends exactly at w2b
  float*          y2b   = oproj;

  const dim3 blk(256);

  cvt_all<<<dim3(2561), blk, 0, stream>>>(x, Wq, Wk, Wv, Wo, W1, W2, bq, bk, bv,
                                          xb, wqkv, wob, w1b, w2b, bqkv);
  // QKV: Q(scaled),K -> qkb; V -> vtb transposed
  gemm_bt<128,1,0,1,0><<<dim3(12, 32), blk, 0, stream>>>(xb, wqkv, bqkv, nullptr, nullptr, qkb, vtb, MR, 1536, DM);
  attn_mfma   <<<dim3(SEQ/128, NB*NH, 4), blk, 0, stream>>>(qkb, vtb, pob, pl);
  attn_combine<<<dim3(MR/4), blk, 0, stream>>>(pob, pl, attnb);
  // O projection, BN=64 split-K x2 -> f32 partials opa (pob region), oproj; 512 blocks
  gemm_bt<64,0,0,0,2><<<dim3(8, 32, 2), blk, 0, stream>>>(attnb, wob, bo, opa, oproj, nullptr, nullptr, MR, DM, DM);
  ln_res<1><<<dim3(MR/4), blk, 0, stream>>>(x, opa, oproj, g1, be1, x1, x1b);
  // FFN1 + ReLU -> bf16 (overlays pob, after ln1 consumed opa)
  gemm_bt<128,1,1,0,0><<<dim3(16, 32), blk, 0, stream>>>(x1b, w1b, b1, f1b, nullptr, nullptr, nullptr, MR, DFF, DM);
  // FFN2, BN=64 split-K x2 -> f32 partials y2a, y2b; 512 blocks
  gemm_bt<64,0,0,0,2><<<dim3(8, 32, 2), blk, 0, stream>>>(f1b, w2b, b2, y2a, y2b, nullptr, nullptr, MR, DM, DFF);
  ln_res<0><<<dim3(MR/4), blk, 0, stream>>>(x1, y2a, y2b, g2, be2, out, nullptr);
}

// Round 13
// 117.176 us; speedup vs baseline: 1.0813x; 1.0813x over previous
//
#include <hip/hip_runtime.h>
#include <hip/hip_bf16.h>
#include <cstddef>

#define SEQ 2048
#define DM  512
#define NH  8
#define DKH 64
#define DFF 2048
#define NB  2
#define MR  (NB*SEQ)   // 4096 rows

typedef __attribute__((ext_vector_type(8)))  short short8;
typedef __attribute__((ext_vector_type(4)))  float f32x4;
typedef __attribute__((ext_vector_type(16))) float f32x16;

#define AS1(p) ((const __attribute__((address_space(1))) void*)(p))
#define AS3(p) ((__attribute__((address_space(3))) void*)(p))

// Q pre-scale: 1/sqrt(64) * log2(e)
#define QSCALE 0.180336880f
// Fixed softmax max (exp2 domain); uniform 2^-SMAX cancels in o/l.
#define SMAX 16.0f

__device__ inline unsigned cvtpk(float lo, float hi) {
  unsigned r;
  asm("v_cvt_pk_bf16_f32 %0, %1, %2" : "=v"(r) : "v"(lo), "v"(hi));
  return r;
}

// ---------------------------------------------------------------------------
// f32 -> bf16 conversion + weight packing
// ---------------------------------------------------------------------------
__device__ inline void cvt8(const float* __restrict__ s, __hip_bfloat16* __restrict__ d) {
  float4 a = *reinterpret_cast<const float4*>(s);
  float4 b = *reinterpret_cast<const float4*>(s + 4);
  union { __hip_bfloat16 h[8]; short8 v; } u;
  u.h[0] = __float2bfloat16(a.x); u.h[1] = __float2bfloat16(a.y);
  u.h[2] = __float2bfloat16(a.z); u.h[3] = __float2bfloat16(a.w);
  u.h[4] = __float2bfloat16(b.x); u.h[5] = __float2bfloat16(b.y);
  u.h[6] = __float2bfloat16(b.z); u.h[7] = __float2bfloat16(b.w);
  *reinterpret_cast<short8*>(d) = u.v;
}

__global__ __launch_bounds__(256) void cvt_all(
    const float* __restrict__ x,
    const float* __restrict__ Wq, const float* __restrict__ Wk,
    const float* __restrict__ Wv, const float* __restrict__ Wo,
    const float* __restrict__ W1, const float* __restrict__ W2,
    const float* __restrict__ bq, const float* __restrict__ bk,
    const float* __restrict__ bv,
    __hip_bfloat16* __restrict__ xb,  __hip_bfloat16* __restrict__ wqkv,
    __hip_bfloat16* __restrict__ wob, __hip_bfloat16* __restrict__ w1b,
    __hip_bfloat16* __restrict__ w2b, float* __restrict__ bqkv)
{
  const int u = blockIdx.x * 256 + threadIdx.x;   // unit of 8 elems
  if (u < 262144) {
    cvt8(x + (size_t)u * 8, xb + (size_t)u * 8);
  } else if (u < 360448) {                         // wqkv: 1536*512 packed
    const int d = (u - 262144) * 8;
    const int n = d >> 9, k = d & 511;
    const float* src = (n < 512) ? (Wq + (size_t)n * 512 + k)
                     : (n < 1024) ? (Wk + (size_t)(n - 512) * 512 + k)
                                  : (Wv + (size_t)(n - 1024) * 512 + k);
    cvt8(src, wqkv + d);
  } else if (u < 393216) {
    const int d = (u - 360448) * 8; cvt8(Wo + d, wob + d);
  } else if (u < 524288) {
    const int d = (u - 393216) * 8; cvt8(W1 + d, w1b + d);
  } else if (u < 655360) {
    const int d = (u - 524288) * 8; cvt8(W2 + d, w2b + d);
  } else if (u < 655552) {
    const int d = (u - 655360) * 8;
    const float* src = (d < 512) ? (bq + d) : (d < 1024) ? (bk + d - 512) : (bv + d - 1024);
    *reinterpret_cast<float4*>(bqkv + d)     = *reinterpret_cast<const float4*>(src);
    *reinterpret_cast<float4*>(bqkv + d + 4) = *reinterpret_cast<const float4*>(src + 4);
  }
}

// ---------------------------------------------------------------------------
// bf16 MFMA GEMM (NT), 128x128 tile, BK=64 double-buffered, 16x16x32 MFMA
// (R10-proven geometry) + T1 XCD-aware block swizzle: same-XCD blocks walk
// consecutive tiles -> A-panel stays in one XCD's L2 instead of 8 copies.
// WVT=1 (QKV): Q*QSCALE,K -> qkbO[4096][1024]; V -> vtO[16][64][2048] transposed.
// SPLITK=2: blockIdx.z K-half -> f32 partials Cout/Cout1, bias in z=0 only.
// ---------------------------------------------------------------------------
template<int OUT_BF16, int RELU, int WVT, int SPLITK>
__global__ __launch_bounds__(256) void gemm_bt(
    const __hip_bfloat16* __restrict__ A, const __hip_bfloat16* __restrict__ Bt,
    const float* __restrict__ bias, void* __restrict__ Cout, void* __restrict__ Cout1,
    __hip_bfloat16* __restrict__ qkbO, __hip_bfloat16* __restrict__ vtO,
    int M, int N, int K)
{
  __shared__ __align__(16) char lds[65536];   // [buf][A 16K | B 16K]
  const int t = threadIdx.x, lane = t & 63, w = t >> 6;

  // T1: bijective XCD swizzle over the (x,y) grid (requires nwg%8==0 — all
  // our grids: 384/512/128). Same-XCD blocks get consecutive tile ids.
  const int nwg = gridDim.x * gridDim.y;
  int bid = blockIdx.y * gridDim.x + blockIdx.x;
  bid = (bid & 7) * (nwg >> 3) + (bid >> 3);
  const int bx = bid % gridDim.x, by = bid / gridDim.x;

  const int m0 = by * 128, n0 = bx * 128;
  const int wm = w >> 1, wn = w & 1;
  const int z = (SPLITK == 2) ? blockIdx.z : 0;
  const int Keff = (SPLITK == 2) ? (K >> 1) : K;
  const int koff = z * Keff;
  const int g = lane >> 4;

  // staging: 32 rows/issue, 8 chunks of 16B per row, source pre-swizzled
  const int r0   = t >> 3;                         // 0..31
  const int kofs = ((lane & 7) ^ (r0 & 7)) * 8;    // elem offset (swizzled)
  const __hip_bfloat16* ap = A  + (size_t)(m0 + r0) * K + koff + kofs;
  const __hip_bfloat16* bp = Bt + (size_t)(n0 + r0) * K + koff + kofs;
  const int ldsoff = t * 16;

  // fragment reads: row*128B + (chunk ^ (row&7))*16
  const int fA = (wm * 64 + (lane & 15)) * 128;
  const int fB = (wn * 64 + (lane & 15)) * 128;
  const int sw = lane & 7;

  f32x4 acc[4][4] = {};
  const int nkt = Keff >> 6;   // K-steps of 64; even for all our shapes

  auto STAGE = [&](int buf, int kt) {
    const size_t ko = (size_t)kt * 64;
    char* bb = lds + buf * 32768;
#pragma unroll
    for (int ii = 0; ii < 4; ++ii) {
      __builtin_amdgcn_global_load_lds(AS1(ap + (size_t)ii * 32 * K + ko), AS3(bb + ii * 4096 + ldsoff),         16, 0, 0);
      __builtin_amdgcn_global_load_lds(AS1(bp + (size_t)ii * 32 * K + ko), AS3(bb + 16384 + ii * 4096 + ldsoff), 16, 0, 0);
    }
  };
  auto COMPUTE = [&](const char* bb) {
    const char* Ab = bb;
    const char* Bb = bb + 16384;
#pragma unroll
    for (int kk = 0; kk < 2; ++kk) {
      const int cx = ((kk * 4 + g) ^ sw) * 16;
      short8 af[4], bf[4];
#pragma unroll
      for (int i = 0; i < 4; ++i) af[i] = *reinterpret_cast<const short8*>(Ab + fA + i * 2048 + cx);
#pragma unroll
      for (int j = 0; j < 4; ++j) bf[j] = *reinterpret_cast<const short8*>(Bb + fB + j * 2048 + cx);
      __builtin_amdgcn_s_setprio(1);
#pragma unroll
      for (int i = 0; i < 4; ++i)
#pragma unroll
        for (int j = 0; j < 4; ++j)
          acc[i][j] = __builtin_amdgcn_mfma_f32_16x16x32_bf16(af[i], bf[j], acc[i][j], 0, 0, 0);
      __builtin_amdgcn_s_setprio(0);
    }
  };

  STAGE(0, 0);
  __syncthreads();
  for (int kt = 0; kt < nkt; kt += 2) {
    STAGE(1, kt + 1 < nkt ? kt + 1 : kt);
    COMPUTE(lds);
    __syncthreads();
    STAGE(0, kt + 2 < nkt ? kt + 2 : kt);   // clamp: dummy in-bounds restage
    COMPUTE(lds + 32768);
    __syncthreads();
  }

  float bcol[4];
#pragma unroll
  for (int j = 0; j < 4; ++j)
    bcol[j] = (SPLITK == 2 && z) ? 0.f : bias[n0 + wn * 64 + j * 16 + (lane & 15)];

  if (WVT && n0 >= 1024) {
#pragma unroll
    for (int i = 0; i < 4; ++i) {
      const int r = m0 + wm * 64 + i * 16 + (g << 2);
      const int bb = r >> 11, s = r & 2047;
#pragma unroll
      for (int j = 0; j < 4; ++j) {
        const int hd = n0 + wn * 64 + j * 16 + (lane & 15) - 1024;
        union { __hip_bfloat16 h[4]; uint2 uu; } pk;
#pragma unroll
        for (int jj = 0; jj < 4; ++jj) pk.h[jj] = __float2bfloat16(acc[i][j][jj] + bcol[j]);
        *reinterpret_cast<uint2*>(vtO + ((size_t)(bb * 8 + (hd >> 6)) * 64 + (hd & 63)) * SEQ + s) = pk.uu;
      }
    }
    return;
  }

  const float qsc = (WVT && n0 < 512) ? QSCALE : 1.0f;
#pragma unroll
  for (int i = 0; i < 4; ++i) {
    const int row = m0 + wm * 64 + i * 16 + (g << 2);
#pragma unroll
    for (int j = 0; j < 4; ++j) {
      const int col = n0 + wn * 64 + j * 16 + (lane & 15);
#pragma unroll
      for (int jj = 0; jj < 4; ++jj) {
        float v = acc[i][j][jj] + bcol[j];
        if (RELU) v = fmaxf(v, 0.f);
        if (WVT)
          qkbO[(size_t)(row + jj) * 1024 + col] = __float2bfloat16(v * qsc);
        else if (OUT_BF16)
          ((__hip_bfloat16*)Cout)[(size_t)(row + jj) * N + col] = __float2bfloat16(v);
        else {
          float* dst = (float*)((SPLITK == 2 && z) ? Cout1 : Cout);
          dst[(size_t)(row + jj) * N + col] = v;
        }
      }
    }
  }
}

// ---------------------------------------------------------------------------
// MFMA flash attention, 32x32 swapped operands, P in registers, FIXED-MAX
// softmax. grid=(16 q-tiles of 128, 16 bh, 4 s-quarters). (unchanged, R10)
// ---------------------------------------------------------------------------
__global__ __launch_bounds__(256) void attn_mfma(
    const __hip_bfloat16* __restrict__ qkb, const __hip_bfloat16* __restrict__ vtb,
    __hip_bfloat16* __restrict__ po, float* __restrict__ pl)
{
  __shared__ __align__(16) char lds[32768];
  char* ks = lds;            // 2 x 8KB K  [64 s][128B d], byte^=(s&7)<<4
  char* vT = lds + 16384;    // 2 x 8KB V^T[64 d][128B s], byte^=(d&7)<<4

  const int t = threadIdx.x, lane = t & 63, w = t >> 6;
  const int qt = blockIdx.x, bh = blockIdx.y, z = blockIdx.z;
  const int b = bh >> 3, h = bh & 7;
  const int ST0 = z * (SEQ / 4);
  const int NT = SEQ / 4 / 64;   // 8 (even)
  const int l31 = lane & 31, hi = lane >> 5;
  const int swz = (lane & 7) << 4;
  const int hi16 = hi * 16;

  const __hip_bfloat16* Qg = qkb + (size_t)b * SEQ * 1024 + h * DKH;
  const int qrow = qt * 128 + w * 32 + l31;
  short8 qf[4];
#pragma unroll
  for (int kc = 0; kc < 4; ++kc)
    qf[kc] = *reinterpret_cast<const short8*>(Qg + (size_t)qrow * 1024 + kc * 16 + hi * 8);

  const int srow = t >> 3;
  const int sofs = ((lane & 7) ^ (srow & 7)) * 8;
  const __hip_bfloat16* kbase = qkb + (size_t)(b * SEQ + ST0 + srow) * 1024 + 512 + h * DKH + sofs;
  const __hip_bfloat16* vbase = vtb + ((size_t)bh * 64 + srow) * SEQ + ST0 + sofs;
  const int ldso = t * 16;

  f32x16 o0 = {}, o1 = {};
  float l_ = 0.f;

  auto STAGE_K = [&](int buf, int st) {
    const size_t ko = (size_t)st * 64 * 1024;
    char* kd = ks + buf * 8192 + ldso;
    __builtin_amdgcn_global_load_lds(AS1(kbase + ko),                     AS3(kd),        16, 0, 0);
    __builtin_amdgcn_global_load_lds(AS1(kbase + ko + (size_t)32 * 1024), AS3(kd + 4096), 16, 0, 0);
  };
  auto STAGE_V = [&](int buf, int st) {
    const size_t vo = (size_t)st * 64;
    char* vd = vT + buf * 8192 + ldso;
    __builtin_amdgcn_global_load_lds(AS1(vbase + vo),                    AS3(vd),        16, 0, 0);
    __builtin_amdgcn_global_load_lds(AS1(vbase + vo + (size_t)32 * SEQ), AS3(vd + 4096), 16, 0, 0);
  };

  auto TILE = [&](const char* kb_, const char* vb_) {
#pragma unroll
    for (int half = 0; half < 2; ++half) {
      const int rbase = (half * 32 + l31) * 128;

      f32x16 acc = {};
      __builtin_amdgcn_s_setprio(1);
#pragma unroll
      for (int kc = 0; kc < 4; ++kc) {
        const int kbyte = (kc * 32 + hi16) ^ swz;
        const short8 ka = *reinterpret_cast<const short8*>(kb_ + rbase + kbyte);
        acc = __builtin_amdgcn_mfma_f32_32x32x16_bf16(ka, qf[kc], acc, 0, 0, 0);
      }
      __builtin_amdgcn_s_setprio(0);

      short8 pf[2];
      float ps = 0.f;
#pragma unroll
      for (int sc = 0; sc < 2; ++sc) {
        const int rb = sc * 8;
        float e0 = exp2f(acc[rb+0] - SMAX), e1 = exp2f(acc[rb+1] - SMAX);
        float e2 = exp2f(acc[rb+2] - SMAX), e3 = exp2f(acc[rb+3] - SMAX);
        float e4 = exp2f(acc[rb+4] - SMAX), e5 = exp2f(acc[rb+5] - SMAX);
        float e6 = exp2f(acc[rb+6] - SMAX), e7 = exp2f(acc[rb+7] - SMAX);
        ps += ((e0 + e1) + (e2 + e3)) + ((e4 + e5) + (e6 + e7));
        unsigned w0 = cvtpk(e0, e1), w1 = cvtpk(e2, e3);
        unsigned w2 = cvtpk(e4, e5), w3 = cvtpk(e6, e7);
        asm("v_permlane32_swap_b32 %0, %1" : "+v"(w0), "+v"(w2));
        asm("v_permlane32_swap_b32 %0, %1" : "+v"(w1), "+v"(w3));
        union { unsigned u[4]; short8 s8; } pu;
        pu.u[0] = w0; pu.u[1] = w1; pu.u[2] = w2; pu.u[3] = w3;
        pf[sc] = pu.s8;
      }
      ps += __shfl_xor(ps, 32);
      l_ += ps;

      __builtin_amdgcn_s_setprio(1);
#pragma unroll
      for (int kc = 0; kc < 2; ++kc) {
        const int sbyte = (half * 64 + kc * 32 + hi16) ^ swz;
        const short8 va0 = *reinterpret_cast<const short8*>(vb_ + l31 * 128 + sbyte);
        const short8 va1 = *reinterpret_cast<const short8*>(vb_ + (32 + l31) * 128 + sbyte);
        o0 = __builtin_amdgcn_mfma_f32_32x32x16_bf16(va0, pf[kc], o0, 0, 0, 0);
        o1 = __builtin_amdgcn_mfma_f32_32x32x16_bf16(va1, pf[kc], o1, 0, 0, 0);
      }
      __builtin_amdgcn_s_setprio(0);
    }
  };

  STAGE_K(0, 0);
  STAGE_V(0, 0);
  __syncthreads();

  for (int st = 0; st < NT; st += 2) {
    STAGE_V(1, st + 1);
    STAGE_K(1, st + 1);
    TILE(ks, vT);
    __syncthreads();
    const int nx = st + 2 < NT ? st + 2 : st + 1;
    STAGE_V(0, nx);
    STAGE_K(0, nx);
    TILE(ks + 8192, vT + 8192);
    __syncthreads();
  }

  {
    __hip_bfloat16* pz = po + (size_t)z * MR * DM;
    const size_t orow = (size_t)b * SEQ + qt * 128 + w * 32 + l31;
    __hip_bfloat16* dst = pz + orow * DM + h * DKH;
#pragma unroll
    for (int r = 0; r < 4; ++r) {
      uint2 u0, u1;
      u0.x = cvtpk(o0[4*r+0], o0[4*r+1]); u0.y = cvtpk(o0[4*r+2], o0[4*r+3]);
      u1.x = cvtpk(o1[4*r+0], o1[4*r+1]); u1.y = cvtpk(o1[4*r+2], o1[4*r+3]);
      *reinterpret_cast<uint2*>(dst + r * 8 + hi * 4)      = u0;
      *reinterpret_cast<uint2*>(dst + 32 + r * 8 + hi * 4) = u1;
    }
  }
  if (lane < 32) {
    const size_t idx = ((size_t)z * 16 + bh) * SEQ + qt * 128 + w * 32 + lane;
    pl[idx] = l_;
  }
}

// ---------------------------------------------------------------------------
// combine four s-quarters (bf16 partials, common fixed-max scale) ->
// attnb bf16 [4096][512]: straight sums, no m-merge.
// ---------------------------------------------------------------------------
__global__ __launch_bounds__(256) void attn_combine(
    const __hip_bfloat16* __restrict__ po, const float* __restrict__ pl,
    __hip_bfloat16* __restrict__ attnb)
{
  const int row  = blockIdx.x * 4 + (threadIdx.x >> 6);
  const int lane = threadIdx.x & 63;
  const int d0 = lane * 8, h = lane >> 3;
  const int b = row >> 11, qq = row & 2047;
  const size_t idx = ((size_t)b * 8 + h) * SEQ + qq;
  const size_t zs = (size_t)16 * SEQ;
  const float inv = 1.0f / (pl[idx] + pl[idx + zs] + pl[idx + 2*zs] + pl[idx + 3*zs]);
  float acc[8] = {};
  const size_t ro = (size_t)row * DM + d0;
#pragma unroll
  for (int zz = 0; zz < 4; ++zz) {
    short8 v = *reinterpret_cast<const short8*>(po + (size_t)zz * MR * DM + ro);
#pragma unroll
    for (int j = 0; j < 8; ++j) {
      const unsigned uu = ((unsigned)(unsigned short)v[j]) << 16;
      acc[j] += __builtin_bit_cast(float, uu);
    }
  }
  union { __hip_bfloat16 hh[8]; short8 s8; } u;
#pragma unroll
  for (int j = 0; j < 8; ++j) u.hh[j] = __float2bfloat16(acc[j] * inv);
  *reinterpret_cast<short8*>(attnb + ro) = u.s8;
}

// ---------------------------------------------------------------------------
// out = LayerNorm(X + Y0 + Y1) * g + be ; optional bf16 copy. One wave/row.
// ---------------------------------------------------------------------------
template<int WB>
__global__ __launch_bounds__(256) void ln_res(
    const float* __restrict__ X, const float* __restrict__ Y0,
    const float* __restrict__ Y1,
    const float* __restrict__ g, const float* __restrict__ be,
    float* __restrict__ out, __hip_bfloat16* __restrict__ outb)
{
  const int row  = blockIdx.x * 4 + (threadIdx.x >> 6);
  const int lane = threadIdx.x & 63;
  const int c0   = lane * 8;
  const float* xr = X  + (size_t)row * DM;
  const float* y0 = Y0 + (size_t)row * DM;
  const float* y1 = Y1 + (size_t)row * DM;

  float v[8];
  float4 a0 = *reinterpret_cast<const float4*>(xr + c0);
  float4 a1 = *reinterpret_cast<const float4*>(xr + c0 + 4);
  float4 b0 = *reinterpret_cast<const float4*>(y0 + c0);
  float4 b1 = *reinterpret_cast<const float4*>(y0 + c0 + 4);
  float4 c0v= *reinterpret_cast<const float4*>(y1 + c0);
  float4 c1v= *reinterpret_cast<const float4*>(y1 + c0 + 4);
  v[0]=a0.x+b0.x+c0v.x; v[1]=a0.y+b0.y+c0v.y; v[2]=a0.z+b0.z+c0v.z; v[3]=a0.w+b0.w+c0v.w;
  v[4]=a1.x+b1.x+c1v.x; v[5]=a1.y+b1.y+c1v.y; v[6]=a1.z+b1.z+c1v.z; v[7]=a1.w+b1.w+c1v.w;

  float s = 0.f;
#pragma unroll
  for (int i = 0; i < 8; ++i) s += v[i];
#pragma unroll
  for (int off = 32; off >= 1; off >>= 1) s += __shfl_xor(s, off);
  const float mu = s * (1.0f/512.0f);

  float ss = 0.f;
#pragma unroll
  for (int i = 0; i < 8; ++i) { const float d = v[i] - mu; ss += d*d; }
#pragma unroll
  for (int off = 32; off >= 1; off >>= 1) ss += __shfl_xor(ss, off);
  const float rs = rsqrtf(ss * (1.0f/512.0f) + 1e-5f);

  float4 g0 = *reinterpret_cast<const float4*>(g  + c0);
  float4 g1 = *reinterpret_cast<const float4*>(g  + c0 + 4);
  float4 e0 = *reinterpret_cast<const float4*>(be + c0);
  float4 e1 = *reinterpret_cast<const float4*>(be + c0 + 4);
  float r[8];
  r[0]=(v[0]-mu)*rs*g0.x+e0.x; r[1]=(v[1]-mu)*rs*g0.y+e0.y;
  r[2]=(v[2]-mu)*rs*g0.z+e0.z; r[3]=(v[3]-mu)*rs*g0.w+e0.w;
  r[4]=(v[4]-mu)*rs*g1.x+e1.x; r[5]=(v[5]-mu)*rs*g1.y+e1.y;
  r[6]=(v[6]-mu)*rs*g1.z+e1.z; r[7]=(v[7]-mu)*rs*g1.w+e1.w;
  float4 o0, o1;
  o0.x=r[0]; o0.y=r[1]; o0.z=r[2]; o0.w=r[3];
  o1.x=r[4]; o1.y=r[5]; o1.z=r[6]; o1.w=r[7];
  *reinterpret_cast<float4*>(out + (size_t)row * DM + c0)     = o0;
  *reinterpret_cast<float4*>(out + (size_t)row * DM + c0 + 4) = o1;
  if (WB) {
    union { __hip_bfloat16 h[8]; short8 vv; } u;
#pragma unroll
    for (int i = 0; i < 8; ++i) u.h[i] = __float2bfloat16(r[i]);
    *reinterpret_cast<short8*>(outb + (size_t)row * DM + c0) = u.vv;
  }
}

// ---------------------------------------------------------------------------
extern "C" void kernel_launch(void* const* d_in, const int* in_sizes, int n_in,
                              void* d_out, int out_size, void* d_ws, size_t ws_size,
                              hipStream_t stream)
{
  const float* x   = (const float*)d_in[0];
  const float* Wq  = (const float*)d_in[1];
  const float* bq  = (const float*)d_in[2];
  const float* Wk  = (const float*)d_in[3];
  const float* bk  = (const float*)d_in[4];
  const float* Wv  = (const float*)d_in[5];
  const float* bv  = (const float*)d_in[6];
  const float* Wo  = (const float*)d_in[7];
  const float* bo  = (const float*)d_in[8];
  const float* W1  = (const float*)d_in[9];
  const float* b1  = (const float*)d_in[10];
  const float* W2  = (const float*)d_in[11];
  const float* b2  = (const float*)d_in[12];
  const float* g1  = (const float*)d_in[13];
  const float* be1 = (const float*)d_in[14];
  const float* g2  = (const float*)d_in[15];
  const float* be2 = (const float*)d_in[16];
  float* out = (float*)d_out;

  // workspace layout (bytes; regions reused across phases)
  char* p = (char*)d_ws;
  __hip_bfloat16* xb    = (__hip_bfloat16*)p;  p += 4194304;   // [4096][512]
  __hip_bfloat16* wqkv  = (__hip_bfloat16*)p;  p += 1572864;   // [1536][512]
  __hip_bfloat16* wob   = (__hip_bfloat16*)p;  p += 524288;    // [512][512]
  __hip_bfloat16* w1b   = (__hip_bfloat16*)p;  p += 2097152;   // [2048][512]
  __hip_bfloat16* w2b   = (__hip_bfloat16*)p;  p += 2097152;   // [512][2048]
  float*          bqkv  = (float*)p;           p += 8192;      // [1536]
  __hip_bfloat16* qkb   = (__hip_bfloat16*)p;  p += 8388608;   // [4096][1024] -> x1 f32
  __hip_bfloat16* vtb   = (__hip_bfloat16*)p;  p += 4194304;   // [16][64][2048] -> attnb
  __hip_bfloat16* pob   = (__hip_bfloat16*)p;  p += 16777216;  // [4][4096][512] bf16 -> opa, f1b
  float*          pl    = (float*)p;           p += 524288;    // [4][16][2048]
  float*          oproj = (float*)p;           p += 8388608;   // oproj z1 / ffn2 z1 partial
  __hip_bfloat16* x1b   = (__hip_bfloat16*)p;  p += 4194304;   // [4096][512]

  float*          x1    = (float*)qkb;            // reuse: qkb dead after attention
  __hip_bfloat16* attnb = (__hip_bfloat16*)vtb;   // reuse: vtb dead after attention
  float*          opa   = (float*)pob;            // pob attn partials dead after combine
  __hip_bfloat16* f1b   = pob;                    // opa dead after ln1
  float*          y2a   = (float*)d_ws;           // [0, 8388608) ends exactly at w2b
  float*          y2b   = oproj;

  const dim3 blk(256);

  cvt_all<<<dim3(2561), blk, 0, stream>>>(x, Wq, Wk, Wv, Wo, W1, W2, bq, bk, bv,
                                          xb, wqkv, wob, w1b, w2b, bqkv);
  // QKV: Q(scaled),K -> qkb; V -> vtb transposed
  gemm_bt<1,0,1,0><<<dim3(12, 32), blk, 0, stream>>>(xb, wqkv, bqkv, nullptr, nullptr, qkb, vtb, MR, 1536, DM);
  attn_mfma   <<<dim3(SEQ/128, NB*NH, 4), blk, 0, stream>>>(qkb, vtb, pob, pl);
  attn_combine<<<dim3(MR/4), blk, 0, stream>>>(pob, pl, attnb);
  // O projection, split-K x2 -> f32 partials opa (pob region), oproj
  gemm_bt<0,0,0,2><<<dim3(4, 32, 2), blk, 0, stream>>>(attnb, wob, bo, opa, oproj, nullptr, nullptr, MR, DM, DM);
  ln_res<1><<<dim3(MR/4), blk, 0, stream>>>(x, opa, oproj, g1, be1, x1, x1b);
  // FFN1 + ReLU -> bf16 (overlays pob, after ln1 consumed opa)
  gemm_bt<1,1,0,0><<<dim3(16, 32), blk, 0, stream>>>(x1b, w1b, b1, f1b, nullptr, nullptr, nullptr, MR, DFF, DM);
  // FFN2, split-K x2 -> f32 partials y2a, y2b
  gemm_bt<0,0,0,2><<<dim3(4, 32, 2), blk, 0, stream>>>(f1b, w2b, b2, y2a, y2b, nullptr, nullptr, MR, DM, DFF);
  ln_res<0><<<dim3(MR/4), blk, 0, stream>>>(x1, y2a, y2b, g2, be2, out, nullptr);
}